// Round 2
// baseline (7932.363 us; speedup 1.0000x reference)
//
#include <hip/hip_runtime.h>
#include <hip/hip_bf16.h>

// QuantizeEncoderLayer: B=8, L=1024, D=1024, H=16, DK=64, DINNER=4096.
// All inputs/outputs are FLOAT32 (reference is jnp.float32 throughout).
#define BSZ   8
#define LSEQ  1024
#define DMOD  1024
#define NHEAD 16
#define DHEAD 64
#define DINN  4096
#define ROWS  (BSZ * LSEQ)   // 8192

typedef __hip_bfloat16 bf16;

__device__ __forceinline__ float ldf(const float* p, size_t i) { return p[i]; }
__device__ __forceinline__ float ldf(const bf16* p, size_t i) {
  return __bfloat162float(p[i]);
}
__device__ __forceinline__ void stf(float* p, size_t i, float v) { p[i] = v; }
__device__ __forceinline__ void stf(bf16* p, size_t i, float v) {
  p[i] = __float2bfloat16(v);
}
// LSQ forward: round-half-even(clamp(x/a, -128, 127)) * a
__device__ __forceinline__ float lsqf(float x, float a) {
  return rintf(fminf(fmaxf(x / a, -128.f), 127.f)) * a;
}

// ---------------------------------------------------------------------------
// Tiled GEMM: C[m,n] = epi( sum_k A[m,k] * qw(W[n,k]) )   (i.e. A @ W^T)
// W always fp32 (model weights). Optional weight LSQ, bias, act LSQ, residual.
// BM=BN=64, BK=16; 256 threads; 4x4 per thread.
// ---------------------------------------------------------------------------
#define BM 64
#define BN 64
#define BK 16

template <typename TA, typename TR, typename TC>
__global__ __launch_bounds__(256) void gemm_q(
    const TA* __restrict__ A, const float* __restrict__ W,
    const float* __restrict__ alpha_w, const float* __restrict__ bias,
    const float* __restrict__ alpha_a, const TR* __restrict__ resid,
    TC* __restrict__ C, int M, int N, int K) {
  __shared__ float As[BM][BK + 1];
  __shared__ float Ws[BN][BK + 1];
  const int tid = threadIdx.x;
  const int bm = blockIdx.y * BM;
  const int bn = blockIdx.x * BN;
  const int tx = tid & 15;
  const int ty = tid >> 4;
  const float aw = alpha_w ? alpha_w[0] : 1.f;

  float acc[4][4] = {};
  for (int k0 = 0; k0 < K; k0 += BK) {
    for (int i = tid; i < BM * BK; i += 256) {
      int r = i >> 4, c = i & 15;
      As[r][c] = ldf(A, (size_t)(bm + r) * K + k0 + c);
    }
    for (int i = tid; i < BN * BK; i += 256) {
      int r = i >> 4, c = i & 15;
      float w = W[(size_t)(bn + r) * K + k0 + c];
      if (alpha_w) w = lsqf(w, aw);
      Ws[r][c] = w;
    }
    __syncthreads();
#pragma unroll
    for (int kk = 0; kk < BK; ++kk) {
      float a[4], b[4];
#pragma unroll
      for (int i = 0; i < 4; ++i) a[i] = As[ty * 4 + i][kk];
#pragma unroll
      for (int j = 0; j < 4; ++j) b[j] = Ws[tx * 4 + j][kk];
#pragma unroll
      for (int i = 0; i < 4; ++i)
#pragma unroll
        for (int j = 0; j < 4; ++j) acc[i][j] += a[i] * b[j];
    }
    __syncthreads();
  }
  const float aa = alpha_a ? alpha_a[0] : 1.f;
#pragma unroll
  for (int i = 0; i < 4; ++i) {
    int m = bm + ty * 4 + i;
#pragma unroll
    for (int j = 0; j < 4; ++j) {
      int n = bn + tx * 4 + j;
      float c = acc[i][j];
      if (bias) c += bias[n];
      if (alpha_a) c = lsqf(c, aa);
      if (resid) c += ldf(resid, (size_t)m * N + n);
      stf(C, (size_t)m * N + n, c);
    }
  }
}

// ---------------------------------------------------------------------------
// Attention pass 1: S[bh, m, n] = (q[m]/8) . k[n]  (per b,h head slice)
// q/k stored (B*L, D) bf16; S written fp32 into the attn output region.
// ---------------------------------------------------------------------------
__global__ __launch_bounds__(256) void attn_scores(const bf16* __restrict__ q,
                                                   const bf16* __restrict__ k,
                                                   float* __restrict__ S) {
  const int bh = blockIdx.z;
  const int b = bh >> 4, h = bh & 15;
  const int bm = blockIdx.y * 64, bn = blockIdx.x * 64;
  __shared__ float Qs[64][17];
  __shared__ float Ks[64][17];
  const int tid = threadIdx.x;
  const int tx = tid & 15, ty = tid >> 4;
  const size_t base = (size_t)b * LSEQ * DMOD + (size_t)h * DHEAD;
  float acc[4][4] = {};
  for (int k0 = 0; k0 < DHEAD; k0 += 16) {
    for (int i = tid; i < 64 * 16; i += 256) {
      int r = i >> 4, c = i & 15;
      Qs[r][c] = ldf(q, base + (size_t)(bm + r) * DMOD + k0 + c) * 0.125f;
      Ks[r][c] = ldf(k, base + (size_t)(bn + r) * DMOD + k0 + c);
    }
    __syncthreads();
#pragma unroll
    for (int kk = 0; kk < 16; ++kk) {
      float a[4], bb[4];
#pragma unroll
      for (int i = 0; i < 4; ++i) a[i] = Qs[ty * 4 + i][kk];
#pragma unroll
      for (int j = 0; j < 4; ++j) bb[j] = Ks[tx * 4 + j][kk];
#pragma unroll
      for (int i = 0; i < 4; ++i)
#pragma unroll
        for (int j = 0; j < 4; ++j) acc[i][j] += a[i] * bb[j];
    }
    __syncthreads();
  }
  const size_t sbase = (size_t)bh * LSEQ * LSEQ;
#pragma unroll
  for (int i = 0; i < 4; ++i)
#pragma unroll
    for (int j = 0; j < 4; ++j)
      S[sbase + (size_t)(bm + ty * 4 + i) * LSEQ + bn + tx * 4 + j] =
          acc[i][j];
}

// Attention pass 2: in-place row softmax over S (one block per row of 1024).
__global__ __launch_bounds__(256) void softmax_rows(float* __restrict__ S) {
  __shared__ float red[256];
  const int tid = threadIdx.x;
  float* row = S + (size_t)blockIdx.x * LSEQ;
  float v[4];
  float m = -1e30f;
#pragma unroll
  for (int c = 0; c < 4; ++c) {
    v[c] = row[c * 256 + tid];
    m = fmaxf(m, v[c]);
  }
  red[tid] = m;
  __syncthreads();
  for (int off = 128; off > 0; off >>= 1) {
    if (tid < off) red[tid] = fmaxf(red[tid], red[tid + off]);
    __syncthreads();
  }
  const float mx = red[0];
  __syncthreads();
  float s = 0.f;
#pragma unroll
  for (int c = 0; c < 4; ++c) {
    v[c] = expf(v[c] - mx);
    s += v[c];
  }
  red[tid] = s;
  __syncthreads();
  for (int off = 128; off > 0; off >>= 1) {
    if (tid < off) red[tid] += red[tid + off];
    __syncthreads();
  }
  const float inv = 1.f / red[0];
#pragma unroll
  for (int c = 0; c < 4; ++c) row[c * 256 + tid] = v[c] * inv;
}

// Attention pass 3: O[m, d] = sum_n P[m,n] * v[n, d]  (per b,h) -> oatt bf16.
__global__ __launch_bounds__(256) void attn_pv(const float* __restrict__ P,
                                               const bf16* __restrict__ v,
                                               bf16* __restrict__ o) {
  const int bh = blockIdx.z;
  const int b = bh >> 4, h = bh & 15;
  const int bm = blockIdx.y * 64;
  __shared__ float Ps[64][17];
  __shared__ float Vs[16][65];
  const int tid = threadIdx.x;
  const int tx = tid & 15, ty = tid >> 4;
  const size_t pbase = (size_t)bh * LSEQ * LSEQ;
  const size_t vbase = (size_t)b * LSEQ * DMOD + (size_t)h * DHEAD;
  float acc[4][4] = {};
  for (int k0 = 0; k0 < LSEQ; k0 += 16) {
    for (int i = tid; i < 64 * 16; i += 256) {
      int r = i >> 4, c = i & 15;
      Ps[r][c] = P[pbase + (size_t)(bm + r) * LSEQ + k0 + c];
    }
    for (int i = tid; i < 16 * 64; i += 256) {
      int r = i >> 6, c = i & 63;
      Vs[r][c] = ldf(v, vbase + (size_t)(k0 + r) * DMOD + c);
    }
    __syncthreads();
#pragma unroll
    for (int kk = 0; kk < 16; ++kk) {
      float a[4], bb[4];
#pragma unroll
      for (int i = 0; i < 4; ++i) a[i] = Ps[ty * 4 + i][kk];
#pragma unroll
      for (int j = 0; j < 4; ++j) bb[j] = Vs[kk][tx * 4 + j];
#pragma unroll
      for (int i = 0; i < 4; ++i)
#pragma unroll
        for (int j = 0; j < 4; ++j) acc[i][j] += a[i] * bb[j];
    }
    __syncthreads();
  }
#pragma unroll
  for (int i = 0; i < 4; ++i)
#pragma unroll
    for (int j = 0; j < 4; ++j)
      stf(o,
          vbase + (size_t)(bm + ty * 4 + i) * DMOD + tx * 4 + j,
          acc[i][j]);
}

// ---------------------------------------------------------------------------
// BatchNorm-as-LN (per-channel stats over 8192 rows), two-stage + apply.
// ---------------------------------------------------------------------------
__global__ __launch_bounds__(256) void bn_partial(const float* __restrict__ X,
                                                  float* __restrict__ psum,
                                                  float* __restrict__ psq) {
  const int c = blockIdx.x * 256 + threadIdx.x;
  const int r0 = blockIdx.y * 256;
  float s = 0.f, q = 0.f;
  for (int r = r0; r < r0 + 256; ++r) {
    float v = X[(size_t)r * DMOD + c];
    s += v;
    q += v * v;
  }
  psum[blockIdx.y * DMOD + c] = s;
  psq[blockIdx.y * DMOD + c] = q;
}

__global__ __launch_bounds__(256) void bn_finalize(
    const float* __restrict__ psum, const float* __restrict__ psq,
    float* __restrict__ meanv, float* __restrict__ rstdv) {
  const int c = blockIdx.x * 256 + threadIdx.x;
  float s = 0.f, q = 0.f;
  for (int j = 0; j < 32; ++j) {
    s += psum[j * DMOD + c];
    q += psq[j * DMOD + c];
  }
  const float m = s / (float)ROWS;
  const float var = q / (float)ROWS - m * m;
  meanv[c] = m;
  rstdv[c] = rsqrtf(var + 1e-6f);
}

template <typename TC>
__global__ __launch_bounds__(256) void bn_apply_lsq(
    const float* __restrict__ X, const float* __restrict__ meanv,
    const float* __restrict__ rstdv, const float* __restrict__ gamma,
    const float* __restrict__ beta, const float* __restrict__ alpha,
    TC* __restrict__ Y) {
  const size_t i = (size_t)blockIdx.x * 256 + threadIdx.x;
  const int c = (int)(i & (DMOD - 1));
  const float aa = alpha[0];
  float o = (X[i] - meanv[c]) * rstdv[c] * gamma[c] + beta[c];
  stf(Y, i, lsqf(o, aa));
}

// ---------------------------------------------------------------------------
extern "C" void kernel_launch(void* const* d_in, const int* in_sizes, int n_in,
                              void* d_out, int out_size, void* d_ws,
                              size_t ws_size, hipStream_t stream) {
  const float* x      = (const float*)d_in[0];
  const float* wq     = (const float*)d_in[1];
  const float* a_wq   = (const float*)d_in[2];
  const float* wk     = (const float*)d_in[3];
  const float* a_wk   = (const float*)d_in[4];
  const float* wv     = (const float*)d_in[5];
  const float* a_wv   = (const float*)d_in[6];
  const float* wo     = (const float*)d_in[7];
  const float* a_wo   = (const float*)d_in[8];
  const float* a1     = (const float*)d_in[9];
  const float* a2     = (const float*)d_in[10];
  const float* a3     = (const float*)d_in[11];
  const float* a4     = (const float*)d_in[12];
  const float* a5     = (const float*)d_in[13];
  const float* bn1_g  = (const float*)d_in[14];
  const float* bn1_b  = (const float*)d_in[15];
  const float* fa1_w1 = (const float*)d_in[16];
  const float* fa1_b1 = (const float*)d_in[17];
  const float* fa1_w2 = (const float*)d_in[18];
  const float* fa1_b2 = (const float*)d_in[19];
  const float* fa1_w3 = (const float*)d_in[20];
  const float* fa1_b3 = (const float*)d_in[21];
  const float* ffn_w1 = (const float*)d_in[22];
  const float* ffn_b1 = (const float*)d_in[23];
  const float* a_fw1  = (const float*)d_in[24];
  const float* ffn_w2 = (const float*)d_in[25];
  const float* ffn_b2 = (const float*)d_in[26];
  const float* a_fw2  = (const float*)d_in[27];
  const float* f1     = (const float*)d_in[28];
  const float* f2     = (const float*)d_in[29];
  const float* f3     = (const float*)d_in[30];
  const float* bn2_g  = (const float*)d_in[31];
  const float* bn2_b  = (const float*)d_in[32];
  const float* fa2_w1 = (const float*)d_in[33];
  const float* fa2_b1 = (const float*)d_in[34];
  const float* fa2_w2 = (const float*)d_in[35];
  const float* fa2_b2 = (const float*)d_in[36];
  const float* fa2_w3 = (const float*)d_in[37];
  const float* fa2_b3 = (const float*)d_in[38];

  // output tuple (fp32): y(8.39M) | attn(134.2M) | fa1(8.39M) | fa2(8.39M)
  float* out = (float*)d_out;
  float* y_out    = out;
  float* attn_out = out + 8388608ull;
  float* fa1_out  = out + 8388608ull + 134217728ull;
  float* fa2_out  = out + 8388608ull + 134217728ull + 8388608ull;

  // workspace (~116.3 MB):
  //  [0,64MB): q,k,v,oatt bf16 (16MB each); later reused as h (8192x4096 bf16)
  //  [64,96MB): t1 fp32 (BN input, also y_pre)
  //  [96,112MB): obn bf16
  //  [112,114): u1 fp32   [114,116): u2 fp32
  //  [116MB+): bn partials / mean / rstd fp32
  char* ws = (char*)d_ws;
  bf16* qws  = (bf16*)(ws + (0ull << 20));
  bf16* kws  = (bf16*)(ws + (16ull << 20));
  bf16* vws  = (bf16*)(ws + (32ull << 20));
  bf16* oatt = (bf16*)(ws + (48ull << 20));
  bf16* hws  = (bf16*)(ws + (0ull << 20));   // overlays q/k/v/oatt
  float* t1  = (float*)(ws + (64ull << 20));
  bf16* obn  = (bf16*)(ws + (96ull << 20));
  float* u1  = (float*)(ws + (112ull << 20));
  float* u2  = (float*)(ws + (114ull << 20));
  float* psum  = (float*)(ws + (116ull << 20));
  float* psq   = psum + 32 * DMOD;
  float* meanv = psq + 32 * DMOD;
  float* rstdv = meanv + DMOD;

  const dim3 blk(256);
  auto grd = [](int M, int N) { return dim3(N / BN, M / BM); };
  const float* nulf = nullptr;

  // q/k/v projections: lsq(x @ lsq(w)^T, a) -> bf16 ws
  gemm_q<float, float, bf16><<<grd(ROWS, DMOD), blk, 0, stream>>>(
      x, wq, a_wq, nullptr, a1, nulf, qws, ROWS, DMOD, DMOD);
  gemm_q<float, float, bf16><<<grd(ROWS, DMOD), blk, 0, stream>>>(
      x, wk, a_wk, nullptr, a2, nulf, kws, ROWS, DMOD, DMOD);
  gemm_q<float, float, bf16><<<grd(ROWS, DMOD), blk, 0, stream>>>(
      x, wv, a_wv, nullptr, a3, nulf, vws, ROWS, DMOD, DMOD);
  // attention: S -> softmax (in d_out) -> PV
  attn_scores<<<dim3(16, 16, 128), blk, 0, stream>>>(qws, kws, attn_out);
  softmax_rows<<<128 * LSEQ, blk, 0, stream>>>(attn_out);
  attn_pv<<<dim3(1, 16, 128), blk, 0, stream>>>(attn_out, vws, oatt);
  // o = lsq(oatt @ lsq(wo)^T, a4) + x  -> t1 (fp32)
  gemm_q<bf16, float, float><<<grd(ROWS, DMOD), blk, 0, stream>>>(
      oatt, wo, a_wo, nullptr, a4, x, t1, ROWS, DMOD, DMOD);
  // bn1 + lsq(a5) -> obn
  bn_partial<<<dim3(DMOD / 256, 32), blk, 0, stream>>>(t1, psum, psq);
  bn_finalize<<<DMOD / 256, blk, 0, stream>>>(psum, psq, meanv, rstdv);
  bn_apply_lsq<bf16><<<ROWS * DMOD / 256, blk, 0, stream>>>(
      t1, meanv, rstdv, bn1_g, bn1_b, a5, obn);
  // fa1 adapter chain + residual
  gemm_q<bf16, float, float><<<grd(ROWS, 64), blk, 0, stream>>>(
      obn, fa1_w1, nullptr, fa1_b1, nullptr, nulf, u1, ROWS, 64, DMOD);
  gemm_q<float, float, float><<<grd(ROWS, 64), blk, 0, stream>>>(
      u1, fa1_w2, nullptr, fa1_b2, nullptr, nulf, u2, ROWS, 64, 64);
  gemm_q<float, bf16, float><<<grd(ROWS, DMOD), blk, 0, stream>>>(
      u2, fa1_w3, nullptr, fa1_b3, nullptr, obn, fa1_out, ROWS, DMOD, 64);
  // FFN
  gemm_q<bf16, float, bf16><<<grd(ROWS, DINN), blk, 0, stream>>>(
      obn, ffn_w1, a_fw1, ffn_b1, f1, nulf, hws, ROWS, DINN, DMOD);
  gemm_q<bf16, bf16, float><<<grd(ROWS, DMOD), blk, 0, stream>>>(
      hws, ffn_w2, a_fw2, ffn_b2, f2, obn, t1, ROWS, DMOD, DINN);
  // bn2 + lsq(f3) -> y (fp32 output)
  bn_partial<<<dim3(DMOD / 256, 32), blk, 0, stream>>>(t1, psum, psq);
  bn_finalize<<<DMOD / 256, blk, 0, stream>>>(psum, psq, meanv, rstdv);
  bn_apply_lsq<float><<<ROWS * DMOD / 256, blk, 0, stream>>>(
      t1, meanv, rstdv, bn2_g, bn2_b, f3, y_out);
  // fa2 adapter chain on y
  gemm_q<float, float, float><<<grd(ROWS, 64), blk, 0, stream>>>(
      y_out, fa2_w1, nullptr, fa2_b1, nullptr, nulf, u1, ROWS, 64, DMOD);
  gemm_q<float, float, float><<<grd(ROWS, 64), blk, 0, stream>>>(
      u1, fa2_w2, nullptr, fa2_b2, nullptr, nulf, u2, ROWS, 64, 64);
  gemm_q<float, float, float><<<grd(ROWS, DMOD), blk, 0, stream>>>(
      u2, fa2_w3, nullptr, fa2_b3, nullptr, y_out, fa2_out, ROWS, DMOD, 64);
}